// Round 1
// baseline (343.646 us; speedup 1.0000x reference)
//
#include <hip/hip_runtime.h>
#include <math.h>

// Problem constants (from reference setup_inputs)
#define NB 4        // batch
#define TT 8192     // sequence length
#define DM 1024     // d_model
#define NH 32       // half = N/2 modes (second 32 are discarded by reference)
#define CT 64       // timesteps per scan chunk (= one wave)
#define NG (TT/CT)  // 128 chunks per sequence
#define DK 128      // k-chunk staged per LDS buffer
#define MW 4        // modes per wave in scan phase (8 waves x 4 modes = 32)

// 16B global->LDS direct copy (wave-uniform LDS base + lane*16 dest)
__device__ __forceinline__ void gload_lds16(const float* g, float* l)
{
    __builtin_amdgcn_global_load_lds(
        (const __attribute__((address_space(1))) void*)g,
        (__attribute__((address_space(3))) void*)l, 16, 0, 0);
}

// ---------------------------------------------------------------------------
// K1: x_proj = x @ W_in^T fused with per-chunk local complex scan.
// Block = 512 threads = 8 waves; lane = t.
// GEMM phase is k-split: wave wv covers k in {ck*128 + 16*wv .. +16} for ALL
// 32 modes (acc[32] per lane), so each staged x element is read from LDS
// exactly once (was 8x). W_in operands are wave-uniform global loads
// (scalar/L1-broadcast path, zero LDS). x tile staged via global_load_lds
// with XOR swizzle: LDS slot (r, c') holds global 16B-chunk c = c' ^ (r&7),
// giving a conflict-optimal single ds_read_b128 per k4-step.
// Partial sums reduced across waves through LDS (reuses xs), then the
// original 64-step wave scan runs unchanged on modes [4wv, 4wv+4).
// ---------------------------------------------------------------------------
__global__ __launch_bounds__(512, 4) void k1_proj_scan(
    const float* __restrict__ x, const float* __restrict__ Wi,
    const float* __restrict__ log_tau, const float* __restrict__ freq,
    const float* __restrict__ log_dt,
    float2* __restrict__ hl, float2* __restrict__ Ech)
{
    __shared__ float xs[2][CT * DK];    // 2 x 32 KB, XOR-swizzled x tiles
    const int c    = blockIdx.x;
    const int b    = blockIdx.y;
    const int t0   = c * CT;
    const int tid  = threadIdx.x;
    const int lane = tid & 63;
    const int wv   = tid >> 6;          // 0..7
    const int wvs  = __builtin_amdgcn_readfirstlane(wv);  // SGPR copy
    const int l7   = lane & 7;

    const float* xb = x + ((size_t)b * TT + t0) * DM;

    float acc[NH];
#pragma unroll
    for (int n = 0; n < NH; ++n) acc[n] = 0.f;

    // staging geometry: wave wv stages rows [8wv, 8wv+8), 4 instrs x 2 rows.
    // lane l of instr i: row r = 8wv + 2i + (l>>5), global 16B-chunk
    // c = (l&31) ^ (r&7) lands at linear LDS slot (r, l&31).
    const int sr0 = (wv << 3) + (lane >> 5);
    const int sc0 = lane & 31;

    // ---- prologue: stage chunk 0 into buf 0
#pragma unroll
    for (int i = 0; i < 4; ++i) {
        const int r  = sr0 + (i << 1);
        const int cc = sc0 ^ (r & 7);
        gload_lds16(xb + (size_t)r * DM + (cc << 2),
                    &xs[0][0] + (((wvs << 3) + (i << 1)) * DK));
    }
    __syncthreads();

    for (int ck = 0; ck < DM / DK; ++ck) {
        // stage next chunk into the other buffer (loads fly under compute;
        // the barrier at loop end drains vmcnt before anyone reads it)
        if (ck + 1 < DM / DK) {
            float* dst = &xs[(ck + 1) & 1][0] + ((wvs << 3) * DK);
#pragma unroll
            for (int i = 0; i < 4; ++i) {
                const int r  = sr0 + (i << 1);
                const int cc = sc0 ^ (r & 7);
                gload_lds16(xb + (size_t)r * DM + (size_t)(ck + 1) * DK + (cc << 2),
                            dst + (i << 1) * DK);
            }
        }
        // compute: this wave covers k4-groups [4wv, 4wv+4) of current chunk
        const char*  xrow = (const char*)(&xs[ck & 1][0]) + lane * (DK * 4);
        const float* wch  = Wi + ck * DK;
#pragma unroll
        for (int s = 0; s < 4; ++s) {
            const int g = (wvs << 2) + s;                 // 16B k-group id
            const float4 xv = *(const float4*)(xrow + ((g ^ l7) << 4));
            const float* wp = wch + (g << 2);
#pragma unroll
            for (int n = 0; n < NH; ++n) {
                const float4 w4 = *(const float4*)(wp + (size_t)n * DM); // uniform
                acc[n] = fmaf(xv.w, w4.w, fmaf(xv.z, w4.z,
                         fmaf(xv.y, w4.y, fmaf(xv.x, w4.x, acc[n]))));
            }
        }
        __syncthreads();
    }

    // ---- cross-wave k-reduction through LDS (reuse xs: 8*32*64 fl = 64 KB)
    float* red = (float*)xs;
#pragma unroll
    for (int n = 0; n < NH; ++n)
        red[(wv << 11) + (n << 6) + lane] = acc[n];
    __syncthreads();

    float am[MW];
#pragma unroll
    for (int j = 0; j < MW; ++j) {
        const int n = wv * MW + j;
        float s = 0.f;
#pragma unroll
        for (int w = 0; w < 8; ++w)
            s += red[(w << 11) + (n << 6) + lane];
        am[j] = s;
    }

    // ---- 64-step inclusive wave scan (Hillis-Steele, lambda^(2^k) by squaring)
    const float dtv = expf(log_dt[0]);
#pragma unroll
    for (int j = 0; j < MW; ++j) {
        const int n = wv * MW + j;
        const float tau = fmaxf(expf(log_tau[n]), 1e-4f);
        const float rr  = expf(-tau * dtv);
        const float th  = freq[n] * dtv;
        float pr = rr * cosf(th), pi = rr * sinf(th);
        float vr = am[j], vi = 0.f;
#pragma unroll
        for (int off = 1; off < 64; off <<= 1) {
            float ur = __shfl_up(vr, (unsigned)off);
            float ui = __shfl_up(vi, (unsigned)off);
            if (lane >= off) {
                vr = fmaf(pr, ur, fmaf(-pi, ui, vr));
                vi = fmaf(pr, ui, fmaf( pi, ur, vi));
            }
            float sr = pr * pr - pi * pi;
            float si = 2.f * pr * pi;
            pr = sr; pi = si;
        }
        // hl layout [b][c][n][t] float2 -> coalesced 512B per mode
        hl[((size_t)(b * NG + c) * NH + n) * CT + lane] = make_float2(vr, vi);
        if (lane == 63) {
            Ech[((size_t)b * NH + n) * NG + c] = make_float2(vr, vi);
        }
    }
}

// ---------------------------------------------------------------------------
// K2: inter-chunk exclusive scan via wave Kogge-Stone. Lane l owns chunks
// {2l, 2l+1}; pair-combine then 6-step scan with ratio Lambda^2.
// Hin[c] = state BEFORE chunk c. Grid = NB blocks x 256 threads.
// ---------------------------------------------------------------------------
__global__ __launch_bounds__(256) void k2_chunkscan(
    const float* __restrict__ log_tau, const float* __restrict__ freq,
    const float* __restrict__ log_dt,
    const float2* __restrict__ Ech, float2* __restrict__ Hin)
{
    const int b    = blockIdx.x;
    const int lane = threadIdx.x & 63;
    const int wv   = threadIdx.x >> 6;      // 0..3, 8 modes each
    const double dtv = exp((double)log_dt[0]);
#pragma unroll
    for (int j = 0; j < 8; ++j) {
        const int n = wv * 8 + j;
        const double tau = fmax(exp((double)log_tau[n]), 1e-4);
        const double a   = (double)freq[n] * dtv * (double)CT;
        const double m   = exp(-tau * dtv * (double)CT);
        const float Lr = (float)(m * cos(a));   // Lambda = lambda^64
        const float Li = (float)(m * sin(a));
        const float2* eb = Ech + ((size_t)b * NH + n) * NG;
        float2 e0 = eb[2 * lane];
        float2 e1 = eb[2 * lane + 1];
        // pair combine: S = Lambda*e0 + e1 (state after chunk 2l from zero)
        float vr = fmaf(Lr, e0.x, fmaf(-Li, e0.y, e1.x));
        float vi = fmaf(Lr, e0.y, fmaf( Li, e0.x, e1.y));
        float pr = Lr * Lr - Li * Li;           // Lambda^2
        float pi = 2.f * Lr * Li;
#pragma unroll
        for (int off = 1; off < 64; off <<= 1) {
            float ur = __shfl_up(vr, (unsigned)off);
            float ui = __shfl_up(vi, (unsigned)off);
            if (lane >= off) {
                vr = fmaf(pr, ur, fmaf(-pi, ui, vr));
                vi = fmaf(pr, ui, fmaf( pi, ur, vi));
            }
            float sr = pr * pr - pi * pi;
            float si = 2.f * pr * pi;
            pr = sr; pi = si;
        }
        // v_l = state after chunk 2l+1; exclusive shift
        float wr = __shfl_up(vr, 1u), wi = __shfl_up(vi, 1u);
        if (lane == 0) { wr = 0.f; wi = 0.f; }
        float2* hb = Hin + ((size_t)b * NH + n) * NG;
        hb[2 * lane]     = make_float2(wr, wi);
        hb[2 * lane + 1] = make_float2(fmaf(Lr, wr, fmaf(-Li, wi, e0.x)),
                                       fmaf(Lr, wi, fmaf( Li, wr, e0.y)));
    }
}

// ---------------------------------------------------------------------------
// K3: combine (h = lambda^(t+1)*H_init + h_local, y = g*Re h) fused with
// output GEMM. 512 threads = 8 waves: wave = (d-quarter qd, t-group tg).
// wT pitch 513 with lane-linear reads (conflict-free); out stores are
// 4 coalesced 256B scalar stores per row.
// ---------------------------------------------------------------------------
__global__ __launch_bounds__(512, 4) void k3_out(
    const float2* __restrict__ hl, const float2* __restrict__ Hin,
    const float* __restrict__ Wo,
    const float* __restrict__ log_tau, const float* __restrict__ freq,
    const float* __restrict__ Bp, const float* __restrict__ Cp,
    const float* __restrict__ log_dt,
    float* __restrict__ out)
{
    __shared__ float ysT[NH * 64];      // 8 KB  [n][t]
    __shared__ float wT[NH * 513];      // 64.1 KB [n][d-in-512-chunk]
    const int c    = blockIdx.x;
    const int b    = blockIdx.y;
    const int t0   = c * CT;
    const int tid  = threadIdx.x;
    const int lane = tid & 63;
    const int wv   = tid >> 6;          // 0..7

    // Phase A: y[t][n] = g * Re(h_local + lambda^(t+1) * H_init); lane = t
    {
        const float dtv = expf(log_dt[0]);
        const int t = lane;
#pragma unroll
        for (int j = 0; j < 4; ++j) {
            const int n = wv * 4 + j;
            const float tau = fmaxf(expf(log_tau[n]), 1e-4f);
            const float rr  = expf(-tau * dtv);
            const float th  = freq[n] * dtv;
            const float g   = (fabsf(Bp[n]) + 1e-9f) * (fabsf(Cp[n]) + 1e-9f);
            float p2r = rr * cosf(th), p2i = rr * sinf(th);
            float pwr = 1.f, pwi = 0.f;
            const int e = t + 1;                 // lambda^(t+1), binary exp
#pragma unroll
            for (int bit = 0; bit < 7; ++bit) {
                if (e & (1 << bit)) {
                    float nr = pwr * p2r - pwi * p2i;
                    float ni = pwr * p2i + pwi * p2r;
                    pwr = nr; pwi = ni;
                }
                float sr = p2r * p2r - p2i * p2i;
                float si = 2.f * p2r * p2i;
                p2r = sr; p2i = si;
            }
            float2 hv = hl[((size_t)(b * NG + c) * NH + n) * CT + t];
            float2 Hv = Hin[((size_t)b * NH + n) * NG + c];
            ysT[n * 64 + t] = g * (hv.x + pwr * Hv.x - pwi * Hv.y);
        }
    }

    // Phase B: out[t][d] = sum_n y[t][n] * Wo[d][n]
    const int qd = wv >> 2;             // d-quarter within 512-chunk
    const int tg = wv & 3;              // rows 16tg..16tg+15
    const int dbase = qd * 256 + lane;
    float* const outb = out + ((size_t)b * TT + t0) * DM;
    for (int db = 0; db < DM; db += 512) {
        __syncthreads();                // ysT ready (1st iter) / wT reuse
        // stage Wo chunk transposed: [n][dl], pitch 513
#pragma unroll
        for (int it = 0; it < 32; ++it) {
            int idx = tid + it * 512;   // 0..16383
            int dl  = idx >> 5;         // 0..511
            int nn  = idx & 31;
            wT[nn * 513 + dl] = Wo[(size_t)(db + dl) * NH + nn];
        }
        __syncthreads();
        float a0[16], a1[16], a2[16], a3[16];
#pragma unroll
        for (int i = 0; i < 16; ++i) { a0[i] = a1[i] = a2[i] = a3[i] = 0.f; }
#pragma unroll 4
        for (int n = 0; n < NH; ++n) {
            const float w0 = wT[n * 513 + dbase];
            const float w1 = wT[n * 513 + dbase + 64];
            const float w2 = wT[n * 513 + dbase + 128];
            const float w3 = wT[n * 513 + dbase + 192];
            const float* yr = &ysT[n * 64 + tg * 16];
#pragma unroll
            for (int i = 0; i < 16; ++i) {
                const float yv = yr[i];
                a0[i] = fmaf(yv, w0, a0[i]);
                a1[i] = fmaf(yv, w1, a1[i]);
                a2[i] = fmaf(yv, w2, a2[i]);
                a3[i] = fmaf(yv, w3, a3[i]);
            }
        }
#pragma unroll
        for (int i = 0; i < 16; ++i) {
            float* op = outb + (size_t)(tg * 16 + i) * DM + db + dbase;
            op[0]   = a0[i];
            op[64]  = a1[i];
            op[128] = a2[i];
            op[192] = a3[i];
        }
    }
}

// ---------------------------------------------------------------------------
// Workspace (floats): hl [NB*NG*NH*CT*2] (8.4 MB) | Ech [NB*NH*NG*2] (128KB)
// | Hin [NB*NH*NG*2] (128KB). Total ~8.65 MB of d_ws.
// ---------------------------------------------------------------------------
extern "C" void kernel_launch(void* const* d_in, const int* in_sizes, int n_in,
                              void* d_out, int out_size, void* d_ws, size_t ws_size,
                              hipStream_t stream)
{
    (void)in_sizes; (void)n_in; (void)out_size; (void)ws_size;
    const float* x       = (const float*)d_in[0];
    const float* log_tau = (const float*)d_in[1];
    const float* freq    = (const float*)d_in[2];
    const float* Bp      = (const float*)d_in[3];
    const float* Cp      = (const float*)d_in[4];
    const float* log_dt  = (const float*)d_in[5];
    const float* Wi      = (const float*)d_in[6];
    const float* Wo      = (const float*)d_in[7];
    float* out = (float*)d_out;

    float2* hl  = (float2*)d_ws;                               // NB*NG*NH*CT
    float2* Ech = hl  + (size_t)NB * NG * NH * CT;             // NB*NH*NG
    float2* Hin = Ech + (size_t)NB * NH * NG;                  // NB*NH*NG

    dim3 grid(NG, NB);
    k1_proj_scan<<<grid, 512, 0, stream>>>(x, Wi, log_tau, freq, log_dt, hl, Ech);
    k2_chunkscan<<<NB, 256, 0, stream>>>(log_tau, freq, log_dt, Ech, Hin);
    k3_out<<<grid, 512, 0, stream>>>(hl, Hin, Wo, log_tau, freq, Bp, Cp, log_dt, out);
}